// Round 1
// baseline (1098.201 us; speedup 1.0000x reference)
//
#include <hip/hip_runtime.h>
#include <hip/hip_bf16.h>

typedef __attribute__((ext_vector_type(8))) short bf16x8;
typedef __attribute__((ext_vector_type(4))) float f32x4;
typedef __attribute__((ext_vector_type(4))) unsigned short us4;

#define S_LEN 2048
#define QKV_P 6144
#define WIN_SZ 1024
#define SCALE_F 0.08838834764831845f
#define LAMBDA_INIT_F 0.35550906759096925f
#define ONE_MINUS_LI_F 0.6444909324090308f

__device__ __forceinline__ unsigned short f2bf(float f) {
    union { float f; unsigned int u; } v; v.f = f;
    unsigned int u = v.u;
    unsigned int r = (u + 0x7fffu + ((u >> 16) & 1u)) >> 16;
    return (unsigned short)r;
}

// ---------------------------------------------------------------------------
// GEMM: C[M x N] = A[M x K] (f32 row-major) * W[N x K]^T (f32 row-major) + bias
// bf16 MFMA inside, fp32 accumulate. BM=BN=128, BK=64, 256 threads (4 waves).
// ---------------------------------------------------------------------------
__global__ __launch_bounds__(256)
void gemm_bf16(const float* __restrict__ A, const float* __restrict__ W,
               const float* __restrict__ bias, float* __restrict__ C,
               int M, int N, int K) {
    constexpr int BM = 128, BN = 128, BK = 64;
    constexpr int PITCH = BK + 8;  // pad: row stride 144B -> 2-way bank alias only
    __shared__ unsigned short As[BM][PITCH];
    __shared__ unsigned short Bs[BN][PITCH];

    const int tid = threadIdx.x;
    const int wid = tid >> 6, lane = tid & 63;
    const int wr = wid >> 1, wc = wid & 1;
    const int l15 = lane & 15, l4 = lane >> 4;
    const int rowBase = blockIdx.y * BM;
    const int colBase = blockIdx.x * BN;

    f32x4 acc[4][4] = {};

    for (int k0 = 0; k0 < K; k0 += BK) {
        // stage A and B tiles: 128x64 f32 each -> bf16 LDS
#pragma unroll
        for (int i = 0; i < 8; ++i) {
            int idx = i * 256 + tid;
            int row = idx >> 4;      // 16 float4 per row
            int c4  = idx & 15;
            float4 va = *(const float4*)(A + (size_t)(rowBase + row) * K + k0 + c4 * 4);
            float4 vb = *(const float4*)(W + (size_t)(colBase + row) * K + k0 + c4 * 4);
            us4 ha, hb;
            ha.x = f2bf(va.x); ha.y = f2bf(va.y); ha.z = f2bf(va.z); ha.w = f2bf(va.w);
            hb.x = f2bf(vb.x); hb.y = f2bf(vb.y); hb.z = f2bf(vb.z); hb.w = f2bf(vb.w);
            *(us4*)&As[row][c4 * 4] = ha;
            *(us4*)&Bs[row][c4 * 4] = hb;
        }
        __syncthreads();

#pragma unroll
        for (int kk = 0; kk < 2; ++kk) {
            bf16x8 af[4], bfv[4];
#pragma unroll
            for (int i = 0; i < 4; ++i)
                af[i] = *(const bf16x8*)&As[wr * 64 + i * 16 + l15][kk * 32 + l4 * 8];
#pragma unroll
            for (int j = 0; j < 4; ++j)
                bfv[j] = *(const bf16x8*)&Bs[wc * 64 + j * 16 + l15][kk * 32 + l4 * 8];
#pragma unroll
            for (int i = 0; i < 4; ++i)
#pragma unroll
                for (int j = 0; j < 4; ++j)
                    acc[i][j] = __builtin_amdgcn_mfma_f32_16x16x32_bf16(af[i], bfv[j], acc[i][j], 0, 0, 0);
        }
        __syncthreads();
    }

#pragma unroll
    for (int i = 0; i < 4; ++i)
#pragma unroll
        for (int j = 0; j < 4; ++j) {
            int n = colBase + wc * 64 + j * 16 + l15;
            float b = bias[n];
#pragma unroll
            for (int r = 0; r < 4; ++r) {
                int m = rowBase + wr * 64 + i * 16 + l4 * 4 + r;
                C[(size_t)m * N + n] = acc[i][j][r] + b;
            }
        }
}

// ---------------------------------------------------------------------------
// RoPE in-place on qkv buffer: q heads 0..31, k heads 32..39 (offset 4096).
// ---------------------------------------------------------------------------
__global__ __launch_bounds__(256)
void rope_kernel(float* __restrict__ qkv, const int* __restrict__ positions) {
    const int row = blockIdx.x;
    const float pos = (float)positions[row];
    for (int idx = threadIdx.x; idx < 40 * 64; idx += 256) {
        int head = idx >> 6;
        int j = idx & 63;
        int base = (head < 32) ? head * 128 : 4096 + (head - 32) * 128;
        // inv_freq = 10000^(-j/64) = exp(-j * ln(10000)/64)
        float inv_freq = __expf(-(float)j * (9.210340371976184f / 64.0f));
        float ang = pos * inv_freq;
        float c = cosf(ang), s = sinf(ang);
        float* p = qkv + (size_t)row * QKV_P + base + j;
        float x1 = p[0], x2 = p[64];
        p[0]  = x1 * c - x2 * s;
        p[64] = x2 * c + x1 * s;
    }
}

// ---------------------------------------------------------------------------
// Dual-stream sliding-window flash attention.
// grid (32 q-tiles, 16 half-heads), 256 threads = 4 waves x 16 q-rows.
// Writes pre-norm combined attn (attn1 - lam*attn2) to attn[row][h*256 + d].
// ---------------------------------------------------------------------------
__global__ __launch_bounds__(256)
void attn_kernel(const float* __restrict__ qkv, float* __restrict__ attn,
                 const float* __restrict__ lq1, const float* __restrict__ lk1,
                 const float* __restrict__ lq2, const float* __restrict__ lk2) {
    __shared__ unsigned short Ks1[64][136];
    __shared__ unsigned short Ks2[64][136];
    __shared__ unsigned short Vt1[128][72];
    __shared__ unsigned short Vt2[128][72];
    __shared__ unsigned short P1[4][16][72];
    __shared__ unsigned short P2[4][16][72];

    const int tid = threadIdx.x;
    const int wid = tid >> 6, lane = tid & 63;
    const int l15 = lane & 15, l4 = lane >> 4;
    const int qtile = blockIdx.x;
    const int h = blockIdx.y;
    const int q0 = qtile * 64;
    const int h1 = 2 * h, h2 = 2 * h + 1;
    const int a1 = 2 * (h >> 2), a2 = a1 + 1;

    // Q fragments (A-operand layout: row = l15, k = kk*32 + l4*8 + j)
    bf16x8 q1f[4], q2f[4];
    {
        int qrow = q0 + wid * 16 + l15;
        const float* qp1 = qkv + (size_t)qrow * QKV_P + h1 * 128;
        const float* qp2 = qkv + (size_t)qrow * QKV_P + h2 * 128;
#pragma unroll
        for (int kk = 0; kk < 4; ++kk) {
            int off = kk * 32 + l4 * 8;
            bf16x8 t1, t2;
#pragma unroll
            for (int j = 0; j < 8; ++j) {
                t1[j] = (short)f2bf(qp1[off + j]);
                t2[j] = (short)f2bf(qp2[off + j]);
            }
            q1f[kk] = t1; q2f[kk] = t2;
        }
    }

    f32x4 a11[8] = {}, a12[8] = {}, a21[8] = {}, a22[8] = {};
    float m1[4], l1[4], m2[4], l2[4];
#pragma unroll
    for (int r = 0; r < 4; ++r) { m1[r] = -1e30f; l1[r] = 0.f; m2[r] = -1e30f; l2[r] = 0.f; }

    const int tbeg = (qtile > 16) ? qtile - 16 : 0;
    for (int t = tbeg; t <= qtile; ++t) {
        const int kv0 = t * 64;
        // stage K1,K2 (row-major padded) and V1,V2 (transposed)
#pragma unroll
        for (int i = 0; i < 8; ++i) {
            int idx = i * 256 + tid;
            int row = idx >> 5;   // 32 float4 per 128-wide row
            int c4  = idx & 31;
            const float* kb = qkv + (size_t)(kv0 + row) * QKV_P + 4096;
            const float* vb = qkv + (size_t)(kv0 + row) * QKV_P + 5120;
            float4 vk1 = *(const float4*)(kb + a1 * 128 + c4 * 4);
            float4 vk2 = *(const float4*)(kb + a2 * 128 + c4 * 4);
            float4 vv1 = *(const float4*)(vb + a1 * 128 + c4 * 4);
            float4 vv2 = *(const float4*)(vb + a2 * 128 + c4 * 4);
            us4 hk1, hk2;
            hk1.x = f2bf(vk1.x); hk1.y = f2bf(vk1.y); hk1.z = f2bf(vk1.z); hk1.w = f2bf(vk1.w);
            hk2.x = f2bf(vk2.x); hk2.y = f2bf(vk2.y); hk2.z = f2bf(vk2.z); hk2.w = f2bf(vk2.w);
            *(us4*)&Ks1[row][c4 * 4] = hk1;
            *(us4*)&Ks2[row][c4 * 4] = hk2;
            int d0 = c4 * 4;
            Vt1[d0 + 0][row] = f2bf(vv1.x); Vt1[d0 + 1][row] = f2bf(vv1.y);
            Vt1[d0 + 2][row] = f2bf(vv1.z); Vt1[d0 + 3][row] = f2bf(vv1.w);
            Vt2[d0 + 0][row] = f2bf(vv2.x); Vt2[d0 + 1][row] = f2bf(vv2.y);
            Vt2[d0 + 2][row] = f2bf(vv2.z); Vt2[d0 + 3][row] = f2bf(vv2.w);
        }
        __syncthreads();

        // QK^T: 16x64 scores per wave per stream
        f32x4 sc1[4], sc2[4];
#pragma unroll
        for (int c = 0; c < 4; ++c) {
            f32x4 s1 = {0.f, 0.f, 0.f, 0.f};
            f32x4 s2 = {0.f, 0.f, 0.f, 0.f};
#pragma unroll
            for (int kk = 0; kk < 4; ++kk) {
                bf16x8 kf1 = *(const bf16x8*)&Ks1[c * 16 + l15][kk * 32 + l4 * 8];
                bf16x8 kf2 = *(const bf16x8*)&Ks2[c * 16 + l15][kk * 32 + l4 * 8];
                s1 = __builtin_amdgcn_mfma_f32_16x16x32_bf16(q1f[kk], kf1, s1, 0, 0, 0);
                s2 = __builtin_amdgcn_mfma_f32_16x16x32_bf16(q2f[kk], kf2, s2, 0, 0, 0);
            }
            sc1[c] = s1; sc2[c] = s2;
        }

        // online softmax, both streams
        float rmax1[4], rmax2[4];
#pragma unroll
        for (int r = 0; r < 4; ++r) { rmax1[r] = -1e30f; rmax2[r] = -1e30f; }
#pragma unroll
        for (int c = 0; c < 4; ++c) {
            int j = kv0 + c * 16 + l15;
#pragma unroll
            for (int r = 0; r < 4; ++r) {
                int i = q0 + wid * 16 + l4 * 4 + r;
                bool valid = (j <= i) && (i - j < WIN_SZ);
                float v1 = valid ? sc1[c][r] * SCALE_F : -1e30f;
                float v2 = valid ? sc2[c][r] * SCALE_F : -1e30f;
                sc1[c][r] = v1; sc2[c][r] = v2;
                rmax1[r] = fmaxf(rmax1[r], v1);
                rmax2[r] = fmaxf(rmax2[r], v2);
            }
        }
#pragma unroll
        for (int msk = 1; msk < 16; msk <<= 1)
#pragma unroll
            for (int r = 0; r < 4; ++r) {
                rmax1[r] = fmaxf(rmax1[r], __shfl_xor(rmax1[r], msk));
                rmax2[r] = fmaxf(rmax2[r], __shfl_xor(rmax2[r], msk));
            }
        float fac1[4], fac2[4], rs1[4], rs2[4];
#pragma unroll
        for (int r = 0; r < 4; ++r) {
            float mn1 = fmaxf(m1[r], rmax1[r]);
            float mn2 = fmaxf(m2[r], rmax2[r]);
            fac1[r] = __expf(m1[r] - mn1);
            fac2[r] = __expf(m2[r] - mn2);
            m1[r] = mn1; m2[r] = mn2; rs1[r] = 0.f; rs2[r] = 0.f;
        }
#pragma unroll
        for (int c = 0; c < 4; ++c) {
            int j = kv0 + c * 16 + l15;
#pragma unroll
            for (int r = 0; r < 4; ++r) {
                int i = q0 + wid * 16 + l4 * 4 + r;
                bool valid = (j <= i) && (i - j < WIN_SZ);
                float p1v = valid ? __expf(sc1[c][r] - m1[r]) : 0.f;
                float p2v = valid ? __expf(sc2[c][r] - m2[r]) : 0.f;
                sc1[c][r] = p1v; sc2[c][r] = p2v;
                rs1[r] += p1v; rs2[r] += p2v;
            }
        }
#pragma unroll
        for (int msk = 1; msk < 16; msk <<= 1)
#pragma unroll
            for (int r = 0; r < 4; ++r) {
                rs1[r] += __shfl_xor(rs1[r], msk);
                rs2[r] += __shfl_xor(rs2[r], msk);
            }
#pragma unroll
        for (int r = 0; r < 4; ++r) {
            l1[r] = l1[r] * fac1[r] + rs1[r];
            l2[r] = l2[r] * fac2[r] + rs2[r];
        }
#pragma unroll
        for (int f = 0; f < 8; ++f)
#pragma unroll
            for (int r = 0; r < 4; ++r) {
                a11[f][r] *= fac1[r]; a12[f][r] *= fac1[r];
                a21[f][r] *= fac2[r]; a22[f][r] *= fac2[r];
            }
        // P -> LDS (per-wave private regions)
#pragma unroll
        for (int c = 0; c < 4; ++c)
#pragma unroll
            for (int r = 0; r < 4; ++r) {
                P1[wid][l4 * 4 + r][c * 16 + l15] = f2bf(sc1[c][r]);
                P2[wid][l4 * 4 + r][c * 16 + l15] = f2bf(sc2[c][r]);
            }
        __syncthreads();

        // PV: acc += P(16x64) x V(64x128)
#pragma unroll
        for (int kk = 0; kk < 2; ++kk) {
            bf16x8 pa1 = *(const bf16x8*)&P1[wid][l15][kk * 32 + l4 * 8];
            bf16x8 pa2 = *(const bf16x8*)&P2[wid][l15][kk * 32 + l4 * 8];
#pragma unroll
            for (int f = 0; f < 8; ++f) {
                bf16x8 vb1 = *(const bf16x8*)&Vt1[f * 16 + l15][kk * 32 + l4 * 8];
                bf16x8 vb2 = *(const bf16x8*)&Vt2[f * 16 + l15][kk * 32 + l4 * 8];
                a11[f] = __builtin_amdgcn_mfma_f32_16x16x32_bf16(pa1, vb1, a11[f], 0, 0, 0);
                a12[f] = __builtin_amdgcn_mfma_f32_16x16x32_bf16(pa1, vb2, a12[f], 0, 0, 0);
                a21[f] = __builtin_amdgcn_mfma_f32_16x16x32_bf16(pa2, vb1, a21[f], 0, 0, 0);
                a22[f] = __builtin_amdgcn_mfma_f32_16x16x32_bf16(pa2, vb2, a22[f], 0, 0, 0);
            }
        }
        __syncthreads();
    }

    // lambda scalar (redundant per lane, 64-lane reduce)
    float s1v = lq1[lane] * lk1[lane] + lq1[lane + 64] * lk1[lane + 64];
    float s2v = lq2[lane] * lk2[lane] + lq2[lane + 64] * lk2[lane + 64];
#pragma unroll
    for (int msk = 1; msk < 64; msk <<= 1) {
        s1v += __shfl_xor(s1v, msk);
        s2v += __shfl_xor(s2v, msk);
    }
    const float lam = __expf(s1v) - __expf(s2v) + LAMBDA_INIT_F;

#pragma unroll
    for (int f = 0; f < 8; ++f)
#pragma unroll
        for (int r = 0; r < 4; ++r) {
            int row = q0 + wid * 16 + l4 * 4 + r;
            float inv1 = 1.0f / l1[r];
            float inv2 = 1.0f / l2[r];
            float o0 = a11[f][r] * inv1 - lam * (a21[f][r] * inv2);
            float o1 = a12[f][r] * inv1 - lam * (a22[f][r] * inv2);
            attn[(size_t)row * 4096 + h * 256 + f * 16 + l15] = o0;
            attn[(size_t)row * 4096 + h * 256 + 128 + f * 16 + l15] = o1;
        }
}

// ---------------------------------------------------------------------------
// RMS-norm over 256 dims per (row, half-head); in-place; includes (1-lambda_init).
// ---------------------------------------------------------------------------
__global__ __launch_bounds__(256)
void norm_kernel(float* __restrict__ attn, const float* __restrict__ subln) {
    const int wid = threadIdx.x >> 6, lane = threadIdx.x & 63;
    const int pair = blockIdx.x * 4 + wid;     // 0 .. 2048*16-1
    const int row = pair >> 4, h = pair & 15;
    float* p = attn + (size_t)row * 4096 + h * 256 + lane * 4;
    float4 v = *(float4*)p;
    float ssq = v.x * v.x + v.y * v.y + v.z * v.z + v.w * v.w;
#pragma unroll
    for (int msk = 1; msk < 64; msk <<= 1) ssq += __shfl_xor(ssq, msk);
    float scale = rsqrtf(ssq * (1.0f / 256.0f) + 1e-5f) * ONE_MINUS_LI_F;
    const float4 sw = *(const float4*)(subln + lane * 4);
    v.x *= scale * sw.x; v.y *= scale * sw.y;
    v.z *= scale * sw.z; v.w *= scale * sw.w;
    *(float4*)p = v;
}

// ---------------------------------------------------------------------------
extern "C" void kernel_launch(void* const* d_in, const int* in_sizes, int n_in,
                              void* d_out, int out_size, void* d_ws, size_t ws_size,
                              hipStream_t stream) {
    const float* hidden    = (const float*)d_in[0];
    const int*   positions = (const int*)d_in[1];
    const float* Wqkv_w    = (const float*)d_in[2];
    const float* Wqkv_b    = (const float*)d_in[3];
    const float* out_w     = (const float*)d_in[4];
    const float* out_b     = (const float*)d_in[5];
    const float* lq1       = (const float*)d_in[6];
    const float* lk1       = (const float*)d_in[7];
    const float* lq2       = (const float*)d_in[8];
    const float* lk2       = (const float*)d_in[9];
    const float* subln     = (const float*)d_in[10];
    float* out = (float*)d_out;

    float* qkv  = (float*)d_ws;                        // 2048 x 6144 f32
    float* attn = qkv + (size_t)S_LEN * QKV_P;         // 2048 x 4096 f32

    // 1) QKV projection
    gemm_bf16<<<dim3(6144 / 128, 2048 / 128), 256, 0, stream>>>(
        hidden, Wqkv_w, Wqkv_b, qkv, 2048, 6144, 4096);
    // 2) RoPE in-place (q + k heads)
    rope_kernel<<<S_LEN, 256, 0, stream>>>(qkv, positions);
    // 3) dual-stream sliding-window attention -> pre-norm combined attn
    attn_kernel<<<dim3(32, 16), 256, 0, stream>>>(qkv, attn, lq1, lk1, lq2, lk2);
    // 4) sub-layernorm (RMS over 256) * (1 - lambda_init)
    norm_kernel<<<S_LEN * 16 / 4, 256, 0, stream>>>(attn, subln);
    // 5) output projection
    gemm_bf16<<<dim3(4096 / 128, 2048 / 128), 256, 0, stream>>>(
        attn, out_w, out_b, out, 2048, 4096, 4096);
}

// Round 2
// 636.632 us; speedup vs baseline: 1.7250x; 1.7250x over previous
//
#include <hip/hip_runtime.h>

typedef unsigned short u16;
typedef __attribute__((ext_vector_type(8))) short bf16x8;
typedef __attribute__((ext_vector_type(4))) float f32x4;
typedef __attribute__((ext_vector_type(4))) unsigned short us4;
typedef __attribute__((ext_vector_type(8))) unsigned short us8;

#define S_LEN 2048
#define QKV_P 6144
#define WIN_SZ 1024
#define SCALE_F 0.08838834764831845f
#define LAMBDA_INIT_F 0.35550906759096925f
#define ONE_MINUS_LI_F 0.6444909324090308f

__device__ __forceinline__ u16 f2bf(float f) {
    union { float f; unsigned int u; } v; v.f = f;
    unsigned int u = v.u;
    return (u16)((u + 0x7fffu + ((u >> 16) & 1u)) >> 16);
}
__device__ __forceinline__ float bf2f(u16 u) {
    union { unsigned int u; float f; } v; v.u = ((unsigned int)u) << 16; return v.f;
}
__device__ __forceinline__ void gload16(const void* g, void* l) {
    __builtin_amdgcn_global_load_lds(
        (const __attribute__((address_space(1))) unsigned int*)g,
        (__attribute__((address_space(3))) unsigned int*)l, 16, 0, 0);
}

// ---------------------------------------------------------------------------
// f32 -> bf16 elementwise convert (vectorized x4)
// ---------------------------------------------------------------------------
__global__ __launch_bounds__(256)
void conv_f32_bf16(const float* __restrict__ src, u16* __restrict__ dst, int n4) {
    for (int i = blockIdx.x * 256 + threadIdx.x; i < n4; i += gridDim.x * 256) {
        float4 v = ((const float4*)src)[i];
        us4 h;
        h.x = f2bf(v.x); h.y = f2bf(v.y); h.z = f2bf(v.z); h.w = f2bf(v.w);
        ((us4*)dst)[i] = h;
    }
}

// ---------------------------------------------------------------------------
// GEMM: C[M x N] = A[M x K] bf16 * W[N x K]^T bf16 + bias(f32)
// m97 structure: BM=BN=128, BK=64, linear LDS, global_load_lds width-16.
// ---------------------------------------------------------------------------
template<int OUT_BF16>
__global__ __launch_bounds__(256)
void gemm_bb(const u16* __restrict__ A, const u16* __restrict__ W,
             const float* __restrict__ bias, void* __restrict__ Cv,
             int M, int N, int K) {
    __shared__ u16 As[128 * 64];
    __shared__ u16 Bs[128 * 64];

    const int tid = threadIdx.x;
    const int wid = tid >> 6, lane = tid & 63;
    const int wr = wid >> 1, wc = wid & 1;
    const int l15 = lane & 15, l4 = lane >> 4;
    const int rowBase = blockIdx.y * 128;
    const int colBase = blockIdx.x * 128;
    const int lr = lane >> 3;        // row within 8-row chunk
    const int lc = (lane & 7) * 8;   // elem col within 64

    f32x4 acc[4][4] = {};

    for (int k0 = 0; k0 < K; k0 += 64) {
        // stage A,B tiles (128x64 bf16 each) via async direct-to-LDS.
        // chunk c = 1024B = 8 rows; LDS dest base is wave-uniform.
#pragma unroll
        for (int s = 0; s < 4; ++s) {
            int c = wid * 4 + s;
            gload16(A + (size_t)(rowBase + c * 8 + lr) * K + k0 + lc, &As[c * 512]);
        }
#pragma unroll
        for (int s = 0; s < 4; ++s) {
            int c = wid * 4 + s;
            gload16(W + (size_t)(colBase + c * 8 + lr) * K + k0 + lc, &Bs[c * 512]);
        }
        __syncthreads();

#pragma unroll
        for (int kk = 0; kk < 2; ++kk) {
            bf16x8 af[4], bfv[4];
#pragma unroll
            for (int i = 0; i < 4; ++i)
                af[i] = *(const bf16x8*)&As[(wr * 64 + i * 16 + l15) * 64 + kk * 32 + l4 * 8];
#pragma unroll
            for (int j = 0; j < 4; ++j)
                bfv[j] = *(const bf16x8*)&Bs[(wc * 64 + j * 16 + l15) * 64 + kk * 32 + l4 * 8];
#pragma unroll
            for (int i = 0; i < 4; ++i)
#pragma unroll
                for (int j = 0; j < 4; ++j)
                    acc[i][j] = __builtin_amdgcn_mfma_f32_16x16x32_bf16(af[i], bfv[j], acc[i][j], 0, 0, 0);
        }
        __syncthreads();
    }

#pragma unroll
    for (int j = 0; j < 4; ++j) {
        int n = colBase + wc * 64 + j * 16 + l15;
        float b = bias[n];
#pragma unroll
        for (int i = 0; i < 4; ++i)
#pragma unroll
            for (int r = 0; r < 4; ++r) {
                int m = rowBase + wr * 64 + i * 16 + l4 * 4 + r;
                float v = acc[i][j][r] + b;
                if (OUT_BF16) ((u16*)Cv)[(size_t)m * N + n] = f2bf(v);
                else          ((float*)Cv)[(size_t)m * N + n] = v;
            }
    }
}

// ---------------------------------------------------------------------------
// RoPE in-place on bf16 qkv: q heads 0..31, k heads 32..39.
// ---------------------------------------------------------------------------
__global__ __launch_bounds__(256)
void rope_bf16(u16* __restrict__ qkv, const int* __restrict__ positions) {
    const int row = blockIdx.x;
    const float pos = (float)positions[row];
    for (int idx = threadIdx.x; idx < 640; idx += 256) {
        int head = idx >> 4;
        int g = idx & 15;
        int base = (head < 32) ? head * 128 : 4096 + (head - 32) * 128;
        u16* p = qkv + (size_t)row * QKV_P + base + g * 4;
        us4 x1 = *(us4*)p;
        us4 x2 = *(us4*)(p + 64);
#pragma unroll
        for (int j = 0; j < 4; ++j) {
            float inv_freq = __expf(-(float)(g * 4 + j) * (9.210340371976184f / 64.0f));
            float ang = pos * inv_freq;
            float s, c;
            sincosf(ang, &s, &c);
            float a = bf2f(x1[j]), b = bf2f(x2[j]);
            x1[j] = f2bf(a * c - b * s);
            x2[j] = f2bf(b * c + a * s);
        }
        *(us4*)p = x1;
        *(us4*)(p + 64) = x2;
    }
}

// ---------------------------------------------------------------------------
// Dual-stream sliding-window flash attention + fused RMS-norm epilogue.
// grid (32 q-tiles, 16 half-head pairs), 256 threads = 4 waves x 16 q-rows.
// Reads bf16 qkv, writes bf16 normalized attn.
// ---------------------------------------------------------------------------
__global__ __launch_bounds__(256)
void attn_bf16(const u16* __restrict__ qkv, u16* __restrict__ attnb,
               const float* __restrict__ lq1, const float* __restrict__ lk1,
               const float* __restrict__ lq2, const float* __restrict__ lk2,
               const float* __restrict__ subln) {
    __shared__ u16 Ks1[64][136];
    __shared__ u16 Ks2[64][136];
    __shared__ u16 Vt1[128][72];
    __shared__ u16 Vt2[128][72];
    __shared__ u16 P1[4][16][72];
    __shared__ u16 P2[4][16][72];

    const int tid = threadIdx.x;
    const int wid = tid >> 6, lane = tid & 63;
    const int l15 = lane & 15, l4 = lane >> 4;
    const int qtile = blockIdx.x;
    const int h = blockIdx.y;
    const int q0 = qtile * 64;
    const int h1 = 2 * h, h2 = 2 * h + 1;
    const int a1 = 2 * (h >> 2), a2 = a1 + 1;

    // Q fragments: direct bf16x8 loads
    bf16x8 q1f[4], q2f[4];
    {
        int qrow = q0 + wid * 16 + l15;
        const u16* qp1 = qkv + (size_t)qrow * QKV_P + h1 * 128;
        const u16* qp2 = qkv + (size_t)qrow * QKV_P + h2 * 128;
#pragma unroll
        for (int kk = 0; kk < 4; ++kk) {
            q1f[kk] = *(const bf16x8*)(qp1 + kk * 32 + l4 * 8);
            q2f[kk] = *(const bf16x8*)(qp2 + kk * 32 + l4 * 8);
        }
    }

    f32x4 a11[8] = {}, a12[8] = {}, a21[8] = {}, a22[8] = {};
    float m1[4], l1[4], m2[4], l2[4];
#pragma unroll
    for (int r = 0; r < 4; ++r) { m1[r] = -1e30f; l1[r] = 0.f; m2[r] = -1e30f; l2[r] = 0.f; }

    const int tbeg = (qtile > 16) ? qtile - 16 : 0;
    for (int t = tbeg; t <= qtile; ++t) {
        const int kv0 = t * 64;
        // stage K1,K2 (row-major padded) and V1,V2 (transposed), bf16 copies
#pragma unroll
        for (int i = 0; i < 4; ++i) {
            int idx = i * 256 + tid;
            int row = idx >> 4;     // 0..63
            int c8 = idx & 15;      // 16 chunks of 8 elems
            const u16* kb = qkv + (size_t)(kv0 + row) * QKV_P + 4096;
            const u16* vb = kb + 1024;
            us8 k1 = *(const us8*)(kb + a1 * 128 + c8 * 8);
            us8 k2 = *(const us8*)(kb + a2 * 128 + c8 * 8);
            *(us8*)&Ks1[row][c8 * 8] = k1;
            *(us8*)&Ks2[row][c8 * 8] = k2;
            us8 v1 = *(const us8*)(vb + a1 * 128 + c8 * 8);
            us8 v2 = *(const us8*)(vb + a2 * 128 + c8 * 8);
            int d0 = c8 * 8;
#pragma unroll
            for (int j = 0; j < 8; ++j) {
                Vt1[d0 + j][row] = v1[j];
                Vt2[d0 + j][row] = v2[j];
            }
        }
        __syncthreads();

        // QK^T
        f32x4 sc1[4], sc2[4];
#pragma unroll
        for (int c = 0; c < 4; ++c) {
            f32x4 s1 = {0.f, 0.f, 0.f, 0.f};
            f32x4 s2 = {0.f, 0.f, 0.f, 0.f};
#pragma unroll
            for (int kk = 0; kk < 4; ++kk) {
                bf16x8 kf1 = *(const bf16x8*)&Ks1[c * 16 + l15][kk * 32 + l4 * 8];
                bf16x8 kf2 = *(const bf16x8*)&Ks2[c * 16 + l15][kk * 32 + l4 * 8];
                s1 = __builtin_amdgcn_mfma_f32_16x16x32_bf16(q1f[kk], kf1, s1, 0, 0, 0);
                s2 = __builtin_amdgcn_mfma_f32_16x16x32_bf16(q2f[kk], kf2, s2, 0, 0, 0);
            }
            sc1[c] = s1; sc2[c] = s2;
        }

        // online softmax, both streams
        float rmax1[4], rmax2[4];
#pragma unroll
        for (int r = 0; r < 4; ++r) { rmax1[r] = -1e30f; rmax2[r] = -1e30f; }
#pragma unroll
        for (int c = 0; c < 4; ++c) {
            int j = kv0 + c * 16 + l15;
#pragma unroll
            for (int r = 0; r < 4; ++r) {
                int i = q0 + wid * 16 + l4 * 4 + r;
                bool valid = (j <= i) && (i - j < WIN_SZ);
                float v1 = valid ? sc1[c][r] * SCALE_F : -1e30f;
                float v2 = valid ? sc2[c][r] * SCALE_F : -1e30f;
                sc1[c][r] = v1; sc2[c][r] = v2;
                rmax1[r] = fmaxf(rmax1[r], v1);
                rmax2[r] = fmaxf(rmax2[r], v2);
            }
        }
#pragma unroll
        for (int msk = 1; msk < 16; msk <<= 1)
#pragma unroll
            for (int r = 0; r < 4; ++r) {
                rmax1[r] = fmaxf(rmax1[r], __shfl_xor(rmax1[r], msk));
                rmax2[r] = fmaxf(rmax2[r], __shfl_xor(rmax2[r], msk));
            }
        float fac1[4], fac2[4], rs1[4], rs2[4];
#pragma unroll
        for (int r = 0; r < 4; ++r) {
            float mn1 = fmaxf(m1[r], rmax1[r]);
            float mn2 = fmaxf(m2[r], rmax2[r]);
            fac1[r] = __expf(m1[r] - mn1);
            fac2[r] = __expf(m2[r] - mn2);
            m1[r] = mn1; m2[r] = mn2; rs1[r] = 0.f; rs2[r] = 0.f;
        }
#pragma unroll
        for (int c = 0; c < 4; ++c) {
            int j = kv0 + c * 16 + l15;
#pragma unroll
            for (int r = 0; r < 4; ++r) {
                int i = q0 + wid * 16 + l4 * 4 + r;
                bool valid = (j <= i) && (i - j < WIN_SZ);
                float p1v = valid ? __expf(sc1[c][r] - m1[r]) : 0.f;
                float p2v = valid ? __expf(sc2[c][r] - m2[r]) : 0.f;
                sc1[c][r] = p1v; sc2[c][r] = p2v;
                rs1[r] += p1v; rs2[r] += p2v;
            }
        }
#pragma unroll
        for (int msk = 1; msk < 16; msk <<= 1)
#pragma unroll
            for (int r = 0; r < 4; ++r) {
                rs1[r] += __shfl_xor(rs1[r], msk);
                rs2[r] += __shfl_xor(rs2[r], msk);
            }
#pragma unroll
        for (int r = 0; r < 4; ++r) {
            l1[r] = l1[r] * fac1[r] + rs1[r];
            l2[r] = l2[r] * fac2[r] + rs2[r];
        }
#pragma unroll
        for (int f = 0; f < 8; ++f)
#pragma unroll
            for (int r = 0; r < 4; ++r) {
                a11[f][r] *= fac1[r]; a12[f][r] *= fac1[r];
                a21[f][r] *= fac2[r]; a22[f][r] *= fac2[r];
            }
#pragma unroll
        for (int c = 0; c < 4; ++c)
#pragma unroll
            for (int r = 0; r < 4; ++r) {
                P1[wid][l4 * 4 + r][c * 16 + l15] = f2bf(sc1[c][r]);
                P2[wid][l4 * 4 + r][c * 16 + l15] = f2bf(sc2[c][r]);
            }
        __syncthreads();

        // PV
#pragma unroll
        for (int kk = 0; kk < 2; ++kk) {
            bf16x8 pa1 = *(const bf16x8*)&P1[wid][l15][kk * 32 + l4 * 8];
            bf16x8 pa2 = *(const bf16x8*)&P2[wid][l15][kk * 32 + l4 * 8];
#pragma unroll
            for (int f = 0; f < 8; ++f) {
                bf16x8 vb1 = *(const bf16x8*)&Vt1[f * 16 + l15][kk * 32 + l4 * 8];
                bf16x8 vb2 = *(const bf16x8*)&Vt2[f * 16 + l15][kk * 32 + l4 * 8];
                a11[f] = __builtin_amdgcn_mfma_f32_16x16x32_bf16(pa1, vb1, a11[f], 0, 0, 0);
                a12[f] = __builtin_amdgcn_mfma_f32_16x16x32_bf16(pa1, vb2, a12[f], 0, 0, 0);
                a21[f] = __builtin_amdgcn_mfma_f32_16x16x32_bf16(pa2, vb1, a21[f], 0, 0, 0);
                a22[f] = __builtin_amdgcn_mfma_f32_16x16x32_bf16(pa2, vb2, a22[f], 0, 0, 0);
            }
        }
        __syncthreads();
    }

    // lambda scalar
    float s1v = lq1[lane] * lk1[lane] + lq1[lane + 64] * lk1[lane + 64];
    float s2v = lq2[lane] * lk2[lane] + lq2[lane + 64] * lk2[lane + 64];
#pragma unroll
    for (int msk = 1; msk < 64; msk <<= 1) {
        s1v += __shfl_xor(s1v, msk);
        s2v += __shfl_xor(s2v, msk);
    }
    const float lam = __expf(s1v) - __expf(s2v) + LAMBDA_INIT_F;

    // subln weights for this thread's columns
    float sw0[8], sw1[8];
#pragma unroll
    for (int f = 0; f < 8; ++f) {
        sw0[f] = subln[f * 16 + l15];
        sw1[f] = subln[128 + f * 16 + l15];
    }

    // epilogue: differential combine + RMS-norm over 256 dims + bf16 store
#pragma unroll
    for (int r = 0; r < 4; ++r) {
        float inv1 = 1.0f / l1[r];
        float inv2 = 1.0f / l2[r];
        float o0[8], o1[8];
        float ssq = 0.f;
#pragma unroll
        for (int f = 0; f < 8; ++f) {
            o0[f] = a11[f][r] * inv1 - lam * (a21[f][r] * inv2);
            o1[f] = a12[f][r] * inv1 - lam * (a22[f][r] * inv2);
            ssq += o0[f] * o0[f] + o1[f] * o1[f];
        }
#pragma unroll
        for (int msk = 1; msk < 16; msk <<= 1) ssq += __shfl_xor(ssq, msk);
        float scale = rsqrtf(ssq * (1.0f / 256.0f) + 1e-5f) * ONE_MINUS_LI_F;
        int row = q0 + wid * 16 + l4 * 4 + r;
        u16* op = attnb + (size_t)row * 4096 + h * 256;
#pragma unroll
        for (int f = 0; f < 8; ++f) {
            op[f * 16 + l15]       = f2bf(o0[f] * scale * sw0[f]);
            op[128 + f * 16 + l15] = f2bf(o1[f] * scale * sw1[f]);
        }
    }
}

// ---------------------------------------------------------------------------
extern "C" void kernel_launch(void* const* d_in, const int* in_sizes, int n_in,
                              void* d_out, int out_size, void* d_ws, size_t ws_size,
                              hipStream_t stream) {
    const float* hidden    = (const float*)d_in[0];
    const int*   positions = (const int*)d_in[1];
    const float* Wqkv_w    = (const float*)d_in[2];
    const float* Wqkv_b    = (const float*)d_in[3];
    const float* out_w     = (const float*)d_in[4];
    const float* out_b     = (const float*)d_in[5];
    const float* lq1       = (const float*)d_in[6];
    const float* lk1       = (const float*)d_in[7];
    const float* lq2       = (const float*)d_in[8];
    const float* lk2       = (const float*)d_in[9];
    const float* subln     = (const float*)d_in[10];
    float* out = (float*)d_out;

    // workspace layout (u16 elems), with reuse:
    //   [0 .. 8.39M)   hidden_bf   -> later reused as attn_bf (same size)
    //   [8.39M .. 33.6M) Wqkv_bf   -> later reused as out_w_bf (smaller)
    //   [33.6M .. 46.1M) qkv_bf
    u16* ws0   = (u16*)d_ws;
    u16* hb    = ws0;
    u16* wqb   = ws0 + 8388608;
    u16* qkvb  = ws0 + 33554432;
    u16* attnb = ws0;          // reuse of hb
    u16* owb   = ws0 + 8388608; // reuse of wqb

    conv_f32_bf16<<<2048, 256, 0, stream>>>(hidden, hb, 2048 * 4096 / 4);
    conv_f32_bf16<<<2048, 256, 0, stream>>>(Wqkv_w, wqb, 6144 * 4096 / 4);

    gemm_bb<1><<<dim3(48, 16), 256, 0, stream>>>(hb, wqb, Wqkv_b, qkvb, 2048, 6144, 4096);

    rope_bf16<<<S_LEN, 256, 0, stream>>>(qkvb, positions);

    conv_f32_bf16<<<2048, 256, 0, stream>>>(out_w, owb, 4096 * 4096 / 4);

    attn_bf16<<<dim3(32, 16), 256, 0, stream>>>(qkvb, attnb, lq1, lk1, lq2, lk2, subln);

    gemm_bb<0><<<dim3(32, 16), 256, 0, stream>>>(attnb, owb, out_b, out, 2048, 4096, 4096);
}

// Round 3
// 515.644 us; speedup vs baseline: 2.1298x; 1.2346x over previous
//
#include <hip/hip_runtime.h>

typedef unsigned short u16;
typedef __attribute__((ext_vector_type(8))) short bf16x8;
typedef __attribute__((ext_vector_type(4))) float f32x4;
typedef __attribute__((ext_vector_type(4))) unsigned short us4;
typedef __attribute__((ext_vector_type(8))) unsigned short us8;

#define S_LEN 2048
#define QKV_P 6144
#define WIN_SZ 1024
#define SCALE_F 0.08838834764831845f
#define LAMBDA_INIT_F 0.35550906759096925f
#define ONE_MINUS_LI_F 0.6444909324090308f

__device__ __forceinline__ u16 f2bf(float f) {
    union { float f; unsigned int u; } v; v.f = f;
    unsigned int u = v.u;
    return (u16)((u + 0x7fffu + ((u >> 16) & 1u)) >> 16);
}
__device__ __forceinline__ float bf2f(u16 u) {
    union { unsigned int u; float f; } v; v.u = ((unsigned int)u) << 16; return v.f;
}
__device__ __forceinline__ void gload16(const void* g, void* l) {
    __builtin_amdgcn_global_load_lds(
        (const __attribute__((address_space(1))) unsigned int*)g,
        (__attribute__((address_space(3))) unsigned int*)l, 16, 0, 0);
}

// ---------------------------------------------------------------------------
// f32 -> bf16 elementwise convert (vectorized x4)
// ---------------------------------------------------------------------------
__global__ __launch_bounds__(256)
void conv_f32_bf16(const float* __restrict__ src, u16* __restrict__ dst, int n4) {
    for (int i = blockIdx.x * 256 + threadIdx.x; i < n4; i += gridDim.x * 256) {
        float4 v = ((const float4*)src)[i];
        us4 h;
        h.x = f2bf(v.x); h.y = f2bf(v.y); h.z = f2bf(v.z); h.w = f2bf(v.w);
        ((us4*)dst)[i] = h;
    }
}

// ---------------------------------------------------------------------------
// GEMM: C[M x N] = A[M x K] bf16 * W[N x K]^T bf16 + bias(f32)
// ---------------------------------------------------------------------------
template<int OUT_BF16>
__global__ __launch_bounds__(256)
void gemm_bb(const u16* __restrict__ A, const u16* __restrict__ W,
             const float* __restrict__ bias, void* __restrict__ Cv,
             int M, int N, int K) {
    __shared__ u16 As[128 * 64];
    __shared__ u16 Bs[128 * 64];

    const int tid = threadIdx.x;
    const int wid = tid >> 6, lane = tid & 63;
    const int wr = wid >> 1, wc = wid & 1;
    const int l15 = lane & 15, l4 = lane >> 4;
    const int rowBase = blockIdx.y * 128;
    const int colBase = blockIdx.x * 128;
    const int lr = lane >> 3;
    const int lc = (lane & 7) * 8;

    f32x4 acc[4][4] = {};

    for (int k0 = 0; k0 < K; k0 += 64) {
#pragma unroll
        for (int s = 0; s < 4; ++s) {
            int c = wid * 4 + s;
            gload16(A + (size_t)(rowBase + c * 8 + lr) * K + k0 + lc, &As[c * 512]);
        }
#pragma unroll
        for (int s = 0; s < 4; ++s) {
            int c = wid * 4 + s;
            gload16(W + (size_t)(colBase + c * 8 + lr) * K + k0 + lc, &Bs[c * 512]);
        }
        __syncthreads();

#pragma unroll
        for (int kk = 0; kk < 2; ++kk) {
            bf16x8 af[4], bfv[4];
#pragma unroll
            for (int i = 0; i < 4; ++i)
                af[i] = *(const bf16x8*)&As[(wr * 64 + i * 16 + l15) * 64 + kk * 32 + l4 * 8];
#pragma unroll
            for (int j = 0; j < 4; ++j)
                bfv[j] = *(const bf16x8*)&Bs[(wc * 64 + j * 16 + l15) * 64 + kk * 32 + l4 * 8];
#pragma unroll
            for (int i = 0; i < 4; ++i)
#pragma unroll
                for (int j = 0; j < 4; ++j)
                    acc[i][j] = __builtin_amdgcn_mfma_f32_16x16x32_bf16(af[i], bfv[j], acc[i][j], 0, 0, 0);
        }
        __syncthreads();
    }

#pragma unroll
    for (int j = 0; j < 4; ++j) {
        int n = colBase + wc * 64 + j * 16 + l15;
        float b = bias[n];
#pragma unroll
        for (int i = 0; i < 4; ++i)
#pragma unroll
            for (int r = 0; r < 4; ++r) {
                int m = rowBase + wr * 64 + i * 16 + l4 * 4 + r;
                float v = acc[i][j][r] + b;
                if (OUT_BF16) ((u16*)Cv)[(size_t)m * N + n] = f2bf(v);
                else          ((float*)Cv)[(size_t)m * N + n] = v;
            }
    }
}

// ---------------------------------------------------------------------------
// RoPE in-place on bf16 qkv: q heads 0..31, k heads 32..39.
// ---------------------------------------------------------------------------
__global__ __launch_bounds__(256)
void rope_bf16(u16* __restrict__ qkv, const int* __restrict__ positions) {
    const int row = blockIdx.x;
    const float pos = (float)positions[row];
    for (int idx = threadIdx.x; idx < 640; idx += 256) {
        int head = idx >> 4;
        int g = idx & 15;
        int base = (head < 32) ? head * 128 : 4096 + (head - 32) * 128;
        u16* p = qkv + (size_t)row * QKV_P + base + g * 4;
        us4 x1 = *(us4*)p;
        us4 x2 = *(us4*)(p + 64);
#pragma unroll
        for (int j = 0; j < 4; ++j) {
            float inv_freq = __expf(-(float)(g * 4 + j) * (9.210340371976184f / 64.0f));
            float ang = pos * inv_freq;
            float s, c;
            sincosf(ang, &s, &c);
            float a = bf2f(x1[j]), b = bf2f(x2[j]);
            x1[j] = f2bf(a * c - b * s);
            x2[j] = f2bf(b * c + a * s);
        }
        *(us4*)p = x1;
        *(us4*)(p + 64) = x2;
    }
}

// ---------------------------------------------------------------------------
// V transpose: qkv V-region -> vt[a][d][s], bf16, chunk-XOR-swizzled LDS tile.
// ---------------------------------------------------------------------------
__global__ __launch_bounds__(256)
void vtrans(const u16* __restrict__ qkv, u16* __restrict__ vt) {
    __shared__ u16 T[128 * 72];
    const int s0 = blockIdx.x * 64;
    const int a = blockIdx.y;
    const u16* src = qkv + 5120 + a * 128;
#pragma unroll
    for (int it = 0; it < 4; ++it) {
        int idx = it * 256 + threadIdx.x;
        int s = idx >> 4;
        int c8 = idx & 15;
        us8 v = *(const us8*)(src + (size_t)(s0 + s) * QKV_P + c8 * 8);
        int sc = s >> 3, su = s & 7;
#pragma unroll
        for (int j = 0; j < 8; ++j) {
            int d = c8 * 8 + j;
            T[d * 72 + ((sc ^ ((d >> 3) & 7)) * 8 + su)] = v[j];
        }
    }
    __syncthreads();
#pragma unroll
    for (int it = 0; it < 4; ++it) {
        int idx = it * 256 + threadIdx.x;
        int d = idx >> 3, sc = idx & 7;
        us8 v = *(const us8*)&T[d * 72 + ((sc ^ ((d >> 3) & 7)) * 8)];
        *(us8*)(vt + (size_t)a * 262144 + (size_t)d * 2048 + s0 + sc * 8) = v;
    }
}

// ---------------------------------------------------------------------------
// Dual-stream sliding-window flash attention + fused RMS-norm epilogue.
// LDS 64KB (K swizzled, Vt swizzled, P aliased onto K) -> 2 blocks/CU.
// ---------------------------------------------------------------------------
__global__ __launch_bounds__(256)
void attn_bf16(const u16* __restrict__ qkv, const u16* __restrict__ vtg,
               u16* __restrict__ attnb,
               const float* __restrict__ lq1, const float* __restrict__ lk1,
               const float* __restrict__ lq2, const float* __restrict__ lk2,
               const float* __restrict__ subln) {
    __shared__ u16 Ks1[64 * 128];
    __shared__ u16 Ks2[64 * 128];
    __shared__ u16 Vs1[128 * 64];
    __shared__ u16 Vs2[128 * 64];
    u16* const P1 = Ks1;   // P aliases K (K dead after QK^T; barrier in between)
    u16* const P2 = Ks2;

    const int tid = threadIdx.x;
    const int wid = tid >> 6, lane = tid & 63;
    const int l15 = lane & 15, l4 = lane >> 4;
    const int qtile = blockIdx.x;
    const int h = blockIdx.y;
    const int q0 = qtile * 64;
    const int h1 = 2 * h, h2 = 2 * h + 1;
    const int a1 = 2 * (h >> 2), a2 = a1 + 1;

    bf16x8 q1f[4], q2f[4];
    {
        int qrow = q0 + wid * 16 + l15;
        const u16* qp1 = qkv + (size_t)qrow * QKV_P + h1 * 128;
        const u16* qp2 = qkv + (size_t)qrow * QKV_P + h2 * 128;
#pragma unroll
        for (int kk = 0; kk < 4; ++kk) {
            q1f[kk] = *(const bf16x8*)(qp1 + kk * 32 + l4 * 8);
            q2f[kk] = *(const bf16x8*)(qp2 + kk * 32 + l4 * 8);
        }
    }

    f32x4 a11[8] = {}, a12[8] = {}, a21[8] = {}, a22[8] = {};
    float m1[4], l1[4], m2[4], l2[4];
#pragma unroll
    for (int r = 0; r < 4; ++r) { m1[r] = -1e30f; l1[r] = 0.f; m2[r] = -1e30f; l2[r] = 0.f; }

    const int kr4 = lane >> 4;          // K staging: row within 4-row chunk
    const int kc  = lane & 15;          // K staging: 16B chunk within 256B row
    const int vd8 = lane >> 3;          // V staging: row within 8-row chunk
    const int vc  = lane & 7;           // V staging: 16B chunk within 128B row

    const int tbeg = (qtile > 16) ? qtile - 16 : 0;
    for (int t = tbeg; t <= qtile; ++t) {
        const int kv0 = t * 64;
#pragma unroll
        for (int s = 0; s < 4; ++s) {
            int ch = wid * 4 + s;
            int krow = ch * 4 + kr4;
            int kcs = (kc ^ (krow & 7)) * 8;
            const u16* kbase = qkv + (size_t)(kv0 + krow) * QKV_P + 4096;
            gload16(kbase + a1 * 128 + kcs, &Ks1[ch * 512]);
            gload16(kbase + a2 * 128 + kcs, &Ks2[ch * 512]);
            int vdrow = ch * 8 + vd8;
            int vcs = (vc ^ (vdrow & 7)) * 8;
            const u16* vbase = vtg + (size_t)vdrow * 2048 + kv0 + vcs;
            gload16(vbase + (size_t)a1 * 262144, &Vs1[ch * 512]);
            gload16(vbase + (size_t)a2 * 262144, &Vs2[ch * 512]);
        }
        __syncthreads();

        f32x4 sc1[4], sc2[4];
#pragma unroll
        for (int c = 0; c < 4; ++c) {
            f32x4 s1 = {0.f, 0.f, 0.f, 0.f};
            f32x4 s2 = {0.f, 0.f, 0.f, 0.f};
#pragma unroll
            for (int kk = 0; kk < 4; ++kk) {
                int off = (c * 16 + l15) * 128 + (((kk * 4 + l4) ^ (l15 & 7)) * 8);
                bf16x8 kf1 = *(const bf16x8*)&Ks1[off];
                bf16x8 kf2 = *(const bf16x8*)&Ks2[off];
                s1 = __builtin_amdgcn_mfma_f32_16x16x32_bf16(q1f[kk], kf1, s1, 0, 0, 0);
                s2 = __builtin_amdgcn_mfma_f32_16x16x32_bf16(q2f[kk], kf2, s2, 0, 0, 0);
            }
            sc1[c] = s1; sc2[c] = s2;
        }
        __syncthreads();   // K reads done before P-store clobbers K region

        float rmax1[4], rmax2[4];
#pragma unroll
        for (int r = 0; r < 4; ++r) { rmax1[r] = -1e30f; rmax2[r] = -1e30f; }
#pragma unroll
        for (int c = 0; c < 4; ++c) {
            int j = kv0 + c * 16 + l15;
#pragma unroll
            for (int r = 0; r < 4; ++r) {
                int i = q0 + wid * 16 + l4 * 4 + r;
                bool valid = (j <= i) && (i - j < WIN_SZ);
                float v1 = valid ? sc1[c][r] * SCALE_F : -1e30f;
                float v2 = valid ? sc2[c][r] * SCALE_F : -1e30f;
                sc1[c][r] = v1; sc2[c][r] = v2;
                rmax1[r] = fmaxf(rmax1[r], v1);
                rmax2[r] = fmaxf(rmax2[r], v2);
            }
        }
#pragma unroll
        for (int msk = 1; msk < 16; msk <<= 1)
#pragma unroll
            for (int r = 0; r < 4; ++r) {
                rmax1[r] = fmaxf(rmax1[r], __shfl_xor(rmax1[r], msk));
                rmax2[r] = fmaxf(rmax2[r], __shfl_xor(rmax2[r], msk));
            }
        float fac1[4], fac2[4], rs1[4], rs2[4];
#pragma unroll
        for (int r = 0; r < 4; ++r) {
            float mn1 = fmaxf(m1[r], rmax1[r]);
            float mn2 = fmaxf(m2[r], rmax2[r]);
            fac1[r] = __expf(m1[r] - mn1);
            fac2[r] = __expf(m2[r] - mn2);
            m1[r] = mn1; m2[r] = mn2; rs1[r] = 0.f; rs2[r] = 0.f;
        }
#pragma unroll
        for (int c = 0; c < 4; ++c) {
            int j = kv0 + c * 16 + l15;
#pragma unroll
            for (int r = 0; r < 4; ++r) {
                int i = q0 + wid * 16 + l4 * 4 + r;
                bool valid = (j <= i) && (i - j < WIN_SZ);
                float p1v = valid ? __expf(sc1[c][r] - m1[r]) : 0.f;
                float p2v = valid ? __expf(sc2[c][r] - m2[r]) : 0.f;
                sc1[c][r] = p1v; sc2[c][r] = p2v;
                rs1[r] += p1v; rs2[r] += p2v;
            }
        }
#pragma unroll
        for (int msk = 1; msk < 16; msk <<= 1)
#pragma unroll
            for (int r = 0; r < 4; ++r) {
                rs1[r] += __shfl_xor(rs1[r], msk);
                rs2[r] += __shfl_xor(rs2[r], msk);
            }
#pragma unroll
        for (int r = 0; r < 4; ++r) {
            l1[r] = l1[r] * fac1[r] + rs1[r];
            l2[r] = l2[r] * fac2[r] + rs2[r];
        }
#pragma unroll
        for (int f = 0; f < 8; ++f)
#pragma unroll
            for (int r = 0; r < 4; ++r) {
                a11[f][r] *= fac1[r]; a12[f][r] *= fac1[r];
                a21[f][r] *= fac2[r]; a22[f][r] *= fac2[r];
            }
#pragma unroll
        for (int c = 0; c < 4; ++c)
#pragma unroll
            for (int r = 0; r < 4; ++r) {
                int prow = (wid * 16 + l4 * 4 + r) * 72 + c * 16 + l15;
                P1[prow] = f2bf(sc1[c][r]);
                P2[prow] = f2bf(sc2[c][r]);
            }

#pragma unroll
        for (int kk = 0; kk < 2; ++kk) {
            bf16x8 pa1 = *(const bf16x8*)&P1[(wid * 16 + l15) * 72 + kk * 32 + l4 * 8];
            bf16x8 pa2 = *(const bf16x8*)&P2[(wid * 16 + l15) * 72 + kk * 32 + l4 * 8];
#pragma unroll
            for (int f = 0; f < 8; ++f) {
                int off = (f * 16 + l15) * 64 + (((kk * 4 + l4) ^ (l15 & 7)) * 8);
                bf16x8 vb1 = *(const bf16x8*)&Vs1[off];
                bf16x8 vb2 = *(const bf16x8*)&Vs2[off];
                a11[f] = __builtin_amdgcn_mfma_f32_16x16x32_bf16(pa1, vb1, a11[f], 0, 0, 0);
                a12[f] = __builtin_amdgcn_mfma_f32_16x16x32_bf16(pa1, vb2, a12[f], 0, 0, 0);
                a21[f] = __builtin_amdgcn_mfma_f32_16x16x32_bf16(pa2, vb1, a21[f], 0, 0, 0);
                a22[f] = __builtin_amdgcn_mfma_f32_16x16x32_bf16(pa2, vb2, a22[f], 0, 0, 0);
            }
        }
        __syncthreads();   // P/V reads done before next tile's staging
    }

    float s1v = lq1[lane] * lk1[lane] + lq1[lane + 64] * lk1[lane + 64];
    float s2v = lq2[lane] * lk2[lane] + lq2[lane + 64] * lk2[lane + 64];
#pragma unroll
    for (int msk = 1; msk < 64; msk <<= 1) {
        s1v += __shfl_xor(s1v, msk);
        s2v += __shfl_xor(s2v, msk);
    }
    const float lam = __expf(s1v) - __expf(s2v) + LAMBDA_INIT_F;

    float sw0[8], sw1[8];
#pragma unroll
    for (int f = 0; f < 8; ++f) {
        sw0[f] = subln[f * 16 + l15];
        sw1[f] = subln[128 + f * 16 + l15];
    }

#pragma unroll
    for (int r = 0; r < 4; ++r) {
        float inv1 = 1.0f / l1[r];
        float inv2 = 1.0f / l2[r];
        float o0[8], o1[8];
        float ssq = 0.f;
#pragma unroll
        for (int f = 0; f < 8; ++f) {
            o0[f] = a11[f][r] * inv1 - lam * (a21[f][r] * inv2);
            o1[f] = a12[f][r] * inv1 - lam * (a22[f][r] * inv2);
            ssq += o0[f] * o0[f] + o1[f] * o1[f];
        }
#pragma unroll
        for (int msk = 1; msk < 16; msk <<= 1) ssq += __shfl_xor(ssq, msk);
        float scale = rsqrtf(ssq * (1.0f / 256.0f) + 1e-5f) * ONE_MINUS_LI_F;
        int row = q0 + wid * 16 + l4 * 4 + r;
        u16* op = attnb + (size_t)row * 4096 + h * 256;
#pragma unroll
        for (int f = 0; f < 8; ++f) {
            op[f * 16 + l15]       = f2bf(o0[f] * scale * sw0[f]);
            op[128 + f * 16 + l15] = f2bf(o1[f] * scale * sw1[f]);
        }
    }
}

// ---------------------------------------------------------------------------
extern "C" void kernel_launch(void* const* d_in, const int* in_sizes, int n_in,
                              void* d_out, int out_size, void* d_ws, size_t ws_size,
                              hipStream_t stream) {
    const float* hidden    = (const float*)d_in[0];
    const int*   positions = (const int*)d_in[1];
    const float* Wqkv_w    = (const float*)d_in[2];
    const float* Wqkv_b    = (const float*)d_in[3];
    const float* out_w     = (const float*)d_in[4];
    const float* out_b     = (const float*)d_in[5];
    const float* lq1       = (const float*)d_in[6];
    const float* lk1       = (const float*)d_in[7];
    const float* lq2       = (const float*)d_in[8];
    const float* lk2       = (const float*)d_in[9];
    const float* subln     = (const float*)d_in[10];
    float* out = (float*)d_out;

    u16* ws0   = (u16*)d_ws;
    u16* hb    = ws0;
    u16* wqb   = ws0 + 8388608;
    u16* qkvb  = ws0 + 33554432;
    u16* attnb = ws0;
    u16* owb   = ws0 + 8388608;
    u16* vt    = ws0 + 25165824;

    conv_f32_bf16<<<2048, 256, 0, stream>>>(hidden, hb, 2048 * 4096 / 4);
    conv_f32_bf16<<<2048, 256, 0, stream>>>(Wqkv_w, wqb, 6144 * 4096 / 4);

    gemm_bb<1><<<dim3(48, 16), 256, 0, stream>>>(hb, wqb, Wqkv_b, qkvb, 2048, 6144, 4096);

    rope_bf16<<<S_LEN, 256, 0, stream>>>(qkvb, positions);
    vtrans<<<dim3(32, 8), 256, 0, stream>>>(qkvb, vt);

    conv_f32_bf16<<<2048, 256, 0, stream>>>(out_w, owb, 4096 * 4096 / 4);

    attn_bf16<<<dim3(32, 16), 256, 0, stream>>>(qkvb, vt, attnb, lq1, lk1, lq2, lk2, subln);

    gemm_bb<0><<<dim3(32, 16), 256, 0, stream>>>(attnb, owb, out_b, out, 2048, 4096, 4096);
}

// Round 4
// 454.182 us; speedup vs baseline: 2.4180x; 1.1353x over previous
//
#include <hip/hip_runtime.h>

typedef unsigned short u16;
typedef __attribute__((ext_vector_type(8))) short bf16x8;
typedef __attribute__((ext_vector_type(4))) float f32x4;
typedef __attribute__((ext_vector_type(4))) unsigned short us4;
typedef __attribute__((ext_vector_type(8))) unsigned short us8;

#define S_LEN 2048
#define QKV_P 6144
#define WIN_SZ 1024
#define SCALE_F 0.08838834764831845f
#define LAMBDA_INIT_F 0.35550906759096925f
#define ONE_MINUS_LI_F 0.6444909324090308f

__device__ __forceinline__ u16 f2bf(float f) {
    union { float f; unsigned int u; } v; v.f = f;
    unsigned int u = v.u;
    return (u16)((u + 0x7fffu + ((u >> 16) & 1u)) >> 16);
}
__device__ __forceinline__ float bf2f(u16 u) {
    union { unsigned int u; float f; } v; v.u = ((unsigned int)u) << 16; return v.f;
}
__device__ __forceinline__ void gload16(const void* g, void* l) {
    __builtin_amdgcn_global_load_lds(
        (const __attribute__((address_space(1))) unsigned int*)g,
        (__attribute__((address_space(3))) unsigned int*)l, 16, 0, 0);
}

// ---------------------------------------------------------------------------
// f32 -> bf16 elementwise convert (vectorized x4)
// ---------------------------------------------------------------------------
__global__ __launch_bounds__(256)
void conv_f32_bf16(const float* __restrict__ src, u16* __restrict__ dst, int n4) {
    for (int i = blockIdx.x * 256 + threadIdx.x; i < n4; i += gridDim.x * 256) {
        float4 v = ((const float4*)src)[i];
        us4 h;
        h.x = f2bf(v.x); h.y = f2bf(v.y); h.z = f2bf(v.z); h.w = f2bf(v.w);
        ((us4*)dst)[i] = h;
    }
}

// ---------------------------------------------------------------------------
// 8-phase 256x256 GEMM: C[M x N] = A[M x K] bf16 * W[N x K]^T bf16 + bias.
// 512 threads = 8 waves (2M x 4N), per-wave output 128x64.
// LDS 128 KB: per parity b (K-tile t&1), per K-half h (cols h*32..h*32+32):
//   A slot [256 rows][32 cols], B slot same. Chunk-XOR swizzle (16B chunks):
//   physical chunk = logical ^ ((row>>1)&3)  -> 2-way bank alias (free).
// Schedule per K-tile t (4 phases, 2 barriers each, counted vmcnt once/tile):
//   p0: read A-k0 m0-3 + B-k0; stage A-k1(t+1)->parity^1 ; MFMA
//   p1: read A-k0 m4-7;        stage B-k1(t+1)->parity^1 ; MFMA
//   p2: read A-k1 m0-3 + B-k1; stage A-k0(t+2)->parity   ; MFMA  (k0 slots dead)
//   p3: read A-k1 m4-7;        stage B-k0(t+2)->parity   ; MFMA; vmcnt(4); bar
// Race-freedom: k0 slots of parity b are only read in p0/p1 of tile t; the
// overwriting stages issue at p2/p3 (barrier-separated). k1(t+1) stages target
// the opposite parity, untouched during tile t.
// ---------------------------------------------------------------------------
__device__ __forceinline__ void stage_half(const u16* __restrict__ src, int K,
                                           int gRowBase, int kcol0,
                                           u16* slot, int tid, int wid) {
#pragma unroll
    for (int g = 0; g < 2; ++g) {
        int row = g * 128 + (tid >> 2);
        int cc = (tid & 3) ^ ((row >> 1) & 3);
        gload16(src + (size_t)(gRowBase + row) * K + kcol0 + cc * 8,
                slot + g * 4096 + wid * 512);
    }
}

__device__ __forceinline__ bf16x8 ldfrag(const u16* slot, int row, int l4) {
    int pc = l4 ^ ((row >> 1) & 3);
    return *(const bf16x8*)(slot + row * 32 + pc * 8);
}

template<int OUT_BF16>
__global__ __launch_bounds__(512, 2)
void gemm8p(const u16* __restrict__ A, const u16* __restrict__ W,
            const float* __restrict__ bias, void* __restrict__ Cv,
            int M, int N, int K, int nbx) {
    __shared__ u16 lds[65536];   // 128 KB

    const int tid = threadIdx.x;
    const int wid = tid >> 6, lane = tid & 63;
    const int wr = wid >> 2, wc = wid & 3;
    const int l15 = lane & 15, l4 = lane >> 4;

    // bijective XCD swizzle (gridDim.x % 8 == 0)
    const int nwg = gridDim.x;
    const int q8 = nwg >> 3;
    const int swz = (blockIdx.x & 7) * q8 + (blockIdx.x >> 3);
    const int bx = swz % nbx, by = swz / nbx;
    const int rowBase = by * 256;
    const int colBase = bx * 256;

    const int NT = K >> 6;

    u16* const baseA = lds;          // 4 slots x 8192 u16
    u16* const baseB = lds + 32768;  // 4 slots x 8192 u16
    // slot(b,h) offset = (b*2+h)*8192

    f32x4 acc[8][4] = {};

    // prologue: k0(0), k1(0), k0(1)
    stage_half(A, K, rowBase, 0,  baseA + 0 * 8192, tid, wid);
    stage_half(W, K, colBase, 0,  baseB + 0 * 8192, tid, wid);
    stage_half(A, K, rowBase, 32, baseA + 1 * 8192, tid, wid);
    stage_half(W, K, colBase, 32, baseB + 1 * 8192, tid, wid);
    if (NT > 1) {
        stage_half(A, K, rowBase, 64, baseA + 2 * 8192, tid, wid);
        stage_half(W, K, colBase, 64, baseB + 2 * 8192, tid, wid);
        asm volatile("s_waitcnt vmcnt(4)" ::: "memory");
    } else {
        asm volatile("s_waitcnt vmcnt(0)" ::: "memory");
    }
    __builtin_amdgcn_s_barrier();

    for (int t = 0; t < NT; ++t) {
        const int b = t & 1;
        const int bn = b ^ 1;
        u16* const A0 = baseA + (b * 2 + 0) * 8192;
        u16* const A1 = baseA + (b * 2 + 1) * 8192;
        u16* const B0 = baseB + (b * 2 + 0) * 8192;
        u16* const B1 = baseB + (b * 2 + 1) * 8192;

        bf16x8 af[4], bfv[4];

        // ---- phase 0: kk0, m0-3
#pragma unroll
        for (int m = 0; m < 4; ++m) af[m] = ldfrag(A0, wr * 128 + m * 16 + l15, l4);
#pragma unroll
        for (int n = 0; n < 4; ++n) bfv[n] = ldfrag(B0, wc * 64 + n * 16 + l15, l4);
        if (t + 1 < NT)
            stage_half(A, K, rowBase, (t + 1) * 64 + 32, baseA + (bn * 2 + 1) * 8192, tid, wid);
        __builtin_amdgcn_s_barrier();
        __builtin_amdgcn_s_setprio(1);
#pragma unroll
        for (int m = 0; m < 4; ++m)
#pragma unroll
            for (int n = 0; n < 4; ++n)
                acc[m][n] = __builtin_amdgcn_mfma_f32_16x16x32_bf16(af[m], bfv[n], acc[m][n], 0, 0, 0);
        __builtin_amdgcn_s_setprio(0);
        __builtin_amdgcn_s_barrier();

        // ---- phase 1: kk0, m4-7 (reuse bfv)
#pragma unroll
        for (int m = 0; m < 4; ++m) af[m] = ldfrag(A0, wr * 128 + (m + 4) * 16 + l15, l4);
        if (t + 1 < NT)
            stage_half(W, K, colBase, (t + 1) * 64 + 32, baseB + (bn * 2 + 1) * 8192, tid, wid);
        __builtin_amdgcn_s_barrier();
        __builtin_amdgcn_s_setprio(1);
#pragma unroll
        for (int m = 0; m < 4; ++m)
#pragma unroll
            for (int n = 0; n < 4; ++n)
                acc[m + 4][n] = __builtin_amdgcn_mfma_f32_16x16x32_bf16(af[m], bfv[n], acc[m + 4][n], 0, 0, 0);
        __builtin_amdgcn_s_setprio(0);
        __builtin_amdgcn_s_barrier();

        // ---- phase 2: kk1, m0-3
#pragma unroll
        for (int m = 0; m < 4; ++m) af[m] = ldfrag(A1, wr * 128 + m * 16 + l15, l4);
#pragma unroll
        for (int n = 0; n < 4; ++n) bfv[n] = ldfrag(B1, wc * 64 + n * 16 + l15, l4);
        if (t + 2 < NT)
            stage_half(A, K, rowBase, (t + 2) * 64, baseA + (b * 2 + 0) * 8192, tid, wid);
        __builtin_amdgcn_s_barrier();
        __builtin_amdgcn_s_setprio(1);
#pragma unroll
        for (int m = 0; m < 4; ++m)
#pragma unroll
            for (int n = 0; n < 4; ++n)
                acc[m][n] = __builtin_amdgcn_mfma_f32_16x16x32_bf16(af[m], bfv[n], acc[m][n], 0, 0, 0);
        __builtin_amdgcn_s_setprio(0);
        __builtin_amdgcn_s_barrier();

        // ---- phase 3: kk1, m4-7
#pragma unroll
        for (int m = 0; m < 4; ++m) af[m] = ldfrag(A1, wr * 128 + (m + 4) * 16 + l15, l4);
        if (t + 2 < NT)
            stage_half(W, K, colBase, (t + 2) * 64, baseB + (b * 2 + 0) * 8192, tid, wid);
        __builtin_amdgcn_s_barrier();
        __builtin_amdgcn_s_setprio(1);
#pragma unroll
        for (int m = 0; m < 4; ++m)
#pragma unroll
            for (int n = 0; n < 4; ++n)
                acc[m + 4][n] = __builtin_amdgcn_mfma_f32_16x16x32_bf16(af[m], bfv[n], acc[m + 4][n], 0, 0, 0);
        __builtin_amdgcn_s_setprio(0);
        if (t + 2 < NT) asm volatile("s_waitcnt vmcnt(4)" ::: "memory");
        else            asm volatile("s_waitcnt vmcnt(0)" ::: "memory");
        __builtin_amdgcn_s_barrier();
    }

    // epilogue
#pragma unroll
    for (int n = 0; n < 4; ++n) {
        int col = colBase + wc * 64 + n * 16 + l15;
        float bs = bias[col];
#pragma unroll
        for (int m = 0; m < 8; ++m)
#pragma unroll
            for (int rr = 0; rr < 4; ++rr) {
                int rowi = rowBase + wr * 128 + m * 16 + l4 * 4 + rr;
                float v = acc[m][n][rr] + bs;
                if (OUT_BF16) ((u16*)Cv)[(size_t)rowi * N + col] = f2bf(v);
                else          ((float*)Cv)[(size_t)rowi * N + col] = v;
            }
    }
}

// ---------------------------------------------------------------------------
// RoPE in-place on bf16 qkv: q heads 0..31, k heads 32..39.
// ---------------------------------------------------------------------------
__global__ __launch_bounds__(256)
void rope_bf16(u16* __restrict__ qkv, const int* __restrict__ positions) {
    const int row = blockIdx.x;
    const float pos = (float)positions[row];
    for (int idx = threadIdx.x; idx < 640; idx += 256) {
        int head = idx >> 4;
        int g = idx & 15;
        int base = (head < 32) ? head * 128 : 4096 + (head - 32) * 128;
        u16* p = qkv + (size_t)row * QKV_P + base + g * 4;
        us4 x1 = *(us4*)p;
        us4 x2 = *(us4*)(p + 64);
#pragma unroll
        for (int j = 0; j < 4; ++j) {
            float inv_freq = __expf(-(float)(g * 4 + j) * (9.210340371976184f / 64.0f));
            float ang = pos * inv_freq;
            float s, c;
            sincosf(ang, &s, &c);
            float a = bf2f(x1[j]), b = bf2f(x2[j]);
            x1[j] = f2bf(a * c - b * s);
            x2[j] = f2bf(b * c + a * s);
        }
        *(us4*)p = x1;
        *(us4*)(p + 64) = x2;
    }
}

// ---------------------------------------------------------------------------
// V transpose: qkv V-region -> vt[a][d][s], bf16, chunk-XOR-swizzled LDS tile.
// ---------------------------------------------------------------------------
__global__ __launch_bounds__(256)
void vtrans(const u16* __restrict__ qkv, u16* __restrict__ vt) {
    __shared__ u16 T[128 * 72];
    const int s0 = blockIdx.x * 64;
    const int a = blockIdx.y;
    const u16* src = qkv + 5120 + a * 128;
#pragma unroll
    for (int it = 0; it < 4; ++it) {
        int idx = it * 256 + threadIdx.x;
        int s = idx >> 4;
        int c8 = idx & 15;
        us8 v = *(const us8*)(src + (size_t)(s0 + s) * QKV_P + c8 * 8);
        int sc = s >> 3, su = s & 7;
#pragma unroll
        for (int j = 0; j < 8; ++j) {
            int d = c8 * 8 + j;
            T[d * 72 + ((sc ^ ((d >> 3) & 7)) * 8 + su)] = v[j];
        }
    }
    __syncthreads();
#pragma unroll
    for (int it = 0; it < 4; ++it) {
        int idx = it * 256 + threadIdx.x;
        int d = idx >> 3, sc = idx & 7;
        us8 v = *(const us8*)&T[d * 72 + ((sc ^ ((d >> 3) & 7)) * 8)];
        *(us8*)(vt + (size_t)a * 262144 + (size_t)d * 2048 + s0 + sc * 8) = v;
    }
}

// ---------------------------------------------------------------------------
// Dual-stream sliding-window flash attention + fused RMS-norm epilogue.
// LDS 64KB (K swizzled, Vt swizzled, P aliased onto K) -> 2 blocks/CU.
// ---------------------------------------------------------------------------
__global__ __launch_bounds__(256)
void attn_bf16(const u16* __restrict__ qkv, const u16* __restrict__ vtg,
               u16* __restrict__ attnb,
               const float* __restrict__ lq1, const float* __restrict__ lk1,
               const float* __restrict__ lq2, const float* __restrict__ lk2,
               const float* __restrict__ subln) {
    __shared__ u16 Ks1[64 * 128];
    __shared__ u16 Ks2[64 * 128];
    __shared__ u16 Vs1[128 * 64];
    __shared__ u16 Vs2[128 * 64];
    u16* const P1 = Ks1;
    u16* const P2 = Ks2;

    const int tid = threadIdx.x;
    const int wid = tid >> 6, lane = tid & 63;
    const int l15 = lane & 15, l4 = lane >> 4;
    const int qtile = blockIdx.x;
    const int h = blockIdx.y;
    const int q0 = qtile * 64;
    const int h1 = 2 * h, h2 = 2 * h + 1;
    const int a1 = 2 * (h >> 2), a2 = a1 + 1;

    bf16x8 q1f[4], q2f[4];
    {
        int qrow = q0 + wid * 16 + l15;
        const u16* qp1 = qkv + (size_t)qrow * QKV_P + h1 * 128;
        const u16* qp2 = qkv + (size_t)qrow * QKV_P + h2 * 128;
#pragma unroll
        for (int kk = 0; kk < 4; ++kk) {
            q1f[kk] = *(const bf16x8*)(qp1 + kk * 32 + l4 * 8);
            q2f[kk] = *(const bf16x8*)(qp2 + kk * 32 + l4 * 8);
        }
    }

    f32x4 a11[8] = {}, a12[8] = {}, a21[8] = {}, a22[8] = {};
    float m1[4], l1[4], m2[4], l2[4];
#pragma unroll
    for (int r = 0; r < 4; ++r) { m1[r] = -1e30f; l1[r] = 0.f; m2[r] = -1e30f; l2[r] = 0.f; }

    const int kr4 = lane >> 4;
    const int kc  = lane & 15;
    const int vd8 = lane >> 3;
    const int vc  = lane & 7;

    const int tbeg = (qtile > 16) ? qtile - 16 : 0;
    for (int t = tbeg; t <= qtile; ++t) {
        const int kv0 = t * 64;
#pragma unroll
        for (int s = 0; s < 4; ++s) {
            int ch = wid * 4 + s;
            int krow = ch * 4 + kr4;
            int kcs = (kc ^ (krow & 7)) * 8;
            const u16* kbase = qkv + (size_t)(kv0 + krow) * QKV_P + 4096;
            gload16(kbase + a1 * 128 + kcs, &Ks1[ch * 512]);
            gload16(kbase + a2 * 128 + kcs, &Ks2[ch * 512]);
            int vdrow = ch * 8 + vd8;
            int vcs = (vc ^ (vdrow & 7)) * 8;
            const u16* vbase = vtg + (size_t)vdrow * 2048 + kv0 + vcs;
            gload16(vbase + (size_t)a1 * 262144, &Vs1[ch * 512]);
            gload16(vbase + (size_t)a2 * 262144, &Vs2[ch * 512]);
        }
        __syncthreads();

        f32x4 sc1[4], sc2[4];
#pragma unroll
        for (int c = 0; c < 4; ++c) {
            f32x4 s1 = {0.f, 0.f, 0.f, 0.f};
            f32x4 s2 = {0.f, 0.f, 0.f, 0.f};
#pragma unroll
            for (int kk = 0; kk < 4; ++kk) {
                int off = (c * 16 + l15) * 128 + (((kk * 4 + l4) ^ (l15 & 7)) * 8);
                bf16x8 kf1 = *(const bf16x8*)&Ks1[off];
                bf16x8 kf2 = *(const bf16x8*)&Ks2[off];
                s1 = __builtin_amdgcn_mfma_f32_16x16x32_bf16(q1f[kk], kf1, s1, 0, 0, 0);
                s2 = __builtin_amdgcn_mfma_f32_16x16x32_bf16(q2f[kk], kf2, s2, 0, 0, 0);
            }
            sc1[c] = s1; sc2[c] = s2;
        }
        __syncthreads();

        float rmax1[4], rmax2[4];
#pragma unroll
        for (int r = 0; r < 4; ++r) { rmax1[r] = -1e30f; rmax2[r] = -1e30f; }
#pragma unroll
        for (int c = 0; c < 4; ++c) {
            int j = kv0 + c * 16 + l15;
#pragma unroll
            for (int r = 0; r < 4; ++r) {
                int i = q0 + wid * 16 + l4 * 4 + r;
                bool valid = (j <= i) && (i - j < WIN_SZ);
                float v1 = valid ? sc1[c][r] * SCALE_F : -1e30f;
                float v2 = valid ? sc2[c][r] * SCALE_F : -1e30f;
                sc1[c][r] = v1; sc2[c][r] = v2;
                rmax1[r] = fmaxf(rmax1[r], v1);
                rmax2[r] = fmaxf(rmax2[r], v2);
            }
        }
#pragma unroll
        for (int msk = 1; msk < 16; msk <<= 1)
#pragma unroll
            for (int r = 0; r < 4; ++r) {
                rmax1[r] = fmaxf(rmax1[r], __shfl_xor(rmax1[r], msk));
                rmax2[r] = fmaxf(rmax2[r], __shfl_xor(rmax2[r], msk));
            }
        float fac1[4], fac2[4], rs1[4], rs2[4];
#pragma unroll
        for (int r = 0; r < 4; ++r) {
            float mn1 = fmaxf(m1[r], rmax1[r]);
            float mn2 = fmaxf(m2[r], rmax2[r]);
            fac1[r] = __expf(m1[r] - mn1);
            fac2[r] = __expf(m2[r] - mn2);
            m1[r] = mn1; m2[r] = mn2; rs1[r] = 0.f; rs2[r] = 0.f;
        }
#pragma unroll
        for (int c = 0; c < 4; ++c) {
            int j = kv0 + c * 16 + l15;
#pragma unroll
            for (int r = 0; r < 4; ++r) {
                int i = q0 + wid * 16 + l4 * 4 + r;
                bool valid = (j <= i) && (i - j < WIN_SZ);
                float p1v = valid ? __expf(sc1[c][r] - m1[r]) : 0.f;
                float p2v = valid ? __expf(sc2[c][r] - m2[r]) : 0.f;
                sc1[c][r] = p1v; sc2[c][r] = p2v;
                rs1[r] += p1v; rs2[r] += p2v;
            }
        }
#pragma unroll
        for (int msk = 1; msk < 16; msk <<= 1)
#pragma unroll
            for (int r = 0; r < 4; ++r) {
                rs1[r] += __shfl_xor(rs1[r], msk);
                rs2[r] += __shfl_xor(rs2[r], msk);
            }
#pragma unroll
        for (int r = 0; r < 4; ++r) {
            l1[r] = l1[r] * fac1[r] + rs1[r];
            l2[r] = l2[r] * fac2[r] + rs2[r];
        }
#pragma unroll
        for (int f = 0; f < 8; ++f)
#pragma unroll
            for (int r = 0; r < 4; ++r) {
                a11[f][r] *= fac1[r]; a12[f][r] *= fac1[r];
                a21[f][r] *= fac2[r]; a22[f][r] *= fac2[r];
            }
#pragma unroll
        for (int c = 0; c < 4; ++c)
#pragma unroll
            for (int r = 0; r < 4; ++r) {
                int prow = (wid * 16 + l4 * 4 + r) * 72 + c * 16 + l15;
                P1[prow] = f2bf(sc1[c][r]);
                P2[prow] = f2bf(sc2[c][r]);
            }

#pragma unroll
        for (int kk = 0; kk < 2; ++kk) {
            bf16x8 pa1 = *(const bf16x8*)&P1[(wid * 16 + l15) * 72 + kk * 32 + l4 * 8];
            bf16x8 pa2 = *(const bf16x8*)&P2[(wid * 16 + l15) * 72 + kk * 32 + l4 * 8];
#pragma unroll
            for (int f = 0; f < 8; ++f) {
                int off = (f * 16 + l15) * 64 + (((kk * 4 + l4) ^ (l15 & 7)) * 8);
                bf16x8 vb1 = *(const bf16x8*)&Vs1[off];
                bf16x8 vb2 = *(const bf16x8*)&Vs2[off];
                a11[f] = __builtin_amdgcn_mfma_f32_16x16x32_bf16(pa1, vb1, a11[f], 0, 0, 0);
                a12[f] = __builtin_amdgcn_mfma_f32_16x16x32_bf16(pa1, vb2, a12[f], 0, 0, 0);
                a21[f] = __builtin_amdgcn_mfma_f32_16x16x32_bf16(pa2, vb1, a21[f], 0, 0, 0);
                a22[f] = __builtin_amdgcn_mfma_f32_16x16x32_bf16(pa2, vb2, a22[f], 0, 0, 0);
            }
        }
        __syncthreads();
    }

    float s1v = lq1[lane] * lk1[lane] + lq1[lane + 64] * lk1[lane + 64];
    float s2v = lq2[lane] * lk2[lane] + lq2[lane + 64] * lk2[lane + 64];
#pragma unroll
    for (int msk = 1; msk < 64; msk <<= 1) {
        s1v += __shfl_xor(s1v, msk);
        s2v += __shfl_xor(s2v, msk);
    }
    const float lam = __expf(s1v) - __expf(s2v) + LAMBDA_INIT_F;

    float sw0[8], sw1[8];
#pragma unroll
    for (int f = 0; f < 8; ++f) {
        sw0[f] = subln[f * 16 + l15];
        sw1[f] = subln[128 + f * 16 + l15];
    }

#pragma unroll
    for (int r = 0; r < 4; ++r) {
        float inv1 = 1.0f / l1[r];
        float inv2 = 1.0f / l2[r];
        float o0[8], o1[8];
        float ssq = 0.f;
#pragma unroll
        for (int f = 0; f < 8; ++f) {
            o0[f] = a11[f][r] * inv1 - lam * (a21[f][r] * inv2);
            o1[f] = a12[f][r] * inv1 - lam * (a22[f][r] * inv2);
            ssq += o0[f] * o0[f] + o1[f] * o1[f];
        }
#pragma unroll
        for (int msk = 1; msk < 16; msk <<= 1) ssq += __shfl_xor(ssq, msk);
        float scale = rsqrtf(ssq * (1.0f / 256.0f) + 1e-5f) * ONE_MINUS_LI_F;
        int row = q0 + wid * 16 + l4 * 4 + r;
        u16* op = attnb + (size_t)row * 4096 + h * 256;
#pragma unroll
        for (int f = 0; f < 8; ++f) {
            op[f * 16 + l15]       = f2bf(o0[f] * scale * sw0[f]);
            op[128 + f * 16 + l15] = f2bf(o1[f] * scale * sw1[f]);
        }
    }
}

// ---------------------------------------------------------------------------
extern "C" void kernel_launch(void* const* d_in, const int* in_sizes, int n_in,
                              void* d_out, int out_size, void* d_ws, size_t ws_size,
                              hipStream_t stream) {
    const float* hidden    = (const float*)d_in[0];
    const int*   positions = (const int*)d_in[1];
    const float* Wqkv_w    = (const float*)d_in[2];
    const float* Wqkv_b    = (const float*)d_in[3];
    const float* out_w     = (const float*)d_in[4];
    const float* out_b     = (const float*)d_in[5];
    const float* lq1       = (const float*)d_in[6];
    const float* lk1       = (const float*)d_in[7];
    const float* lq2       = (const float*)d_in[8];
    const float* lk2       = (const float*)d_in[9];
    const float* subln     = (const float*)d_in[10];
    float* out = (float*)d_out;

    u16* ws0   = (u16*)d_ws;
    u16* hb    = ws0;
    u16* wqb   = ws0 + 8388608;
    u16* qkvb  = ws0 + 33554432;
    u16* attnb = ws0;
    u16* owb   = ws0 + 8388608;
    u16* vt    = ws0 + 25165824;

    conv_f32_bf16<<<2048, 256, 0, stream>>>(hidden, hb, 2048 * 4096 / 4);
    conv_f32_bf16<<<2048, 256, 0, stream>>>(Wqkv_w, wqb, 6144 * 4096 / 4);

    // QKV projection: M=2048, N=6144, K=4096 -> 8x24 = 192 blocks (192%8==0)
    gemm8p<1><<<192, 512, 0, stream>>>(hb, wqb, Wqkv_b, qkvb, 2048, 6144, 4096, 24);

    rope_bf16<<<S_LEN, 256, 0, stream>>>(qkvb, positions);
    vtrans<<<dim3(32, 8), 256, 0, stream>>>(qkvb, vt);

    conv_f32_bf16<<<2048, 256, 0, stream>>>(out_w, owb, 4096 * 4096 / 4);

    attn_bf16<<<dim3(32, 16), 256, 0, stream>>>(qkvb, vt, attnb, lq1, lk1, lq2, lk2, subln);

    // out projection: M=2048, N=4096, K=4096 -> 8x16 = 128 blocks (128%8==0)
    gemm8p<0><<<128, 512, 0, stream>>>(attnb, owb, out_b, out, 2048, 4096, 4096, 16);
}